// Round 12
// baseline (644.872 us; speedup 1.0000x reference)
//
#include <hip/hip_runtime.h>
#include <stdint.h>

typedef short bf16x8 __attribute__((ext_vector_type(8)));
typedef float f32x4 __attribute__((ext_vector_type(4)));
typedef unsigned short u16;

__device__ __forceinline__ float b2f(u16 u) {
  return __uint_as_float(((unsigned)u) << 16);
}
__device__ __forceinline__ u16 f2b(float f) {
  unsigned u = __float_as_uint(f);
  return (u16)((u + 0x7fffu + ((u >> 16) & 1u)) >> 16);  // RNE
}

#define NEGINF (-1.0e30f)

__device__ __forceinline__ void gld_lds16(const u16* g, u16* l) {
  __builtin_amdgcn_global_load_lds(
      (const __attribute__((address_space(1))) unsigned int*)(const void*)g,
      (__attribute__((address_space(3))) unsigned int*)(void*)l, 16, 0, 0);
}

// swizzles: XOR 16B-chunk bits with row&7. Involutions.
__device__ __forceinline__ int swzV(int o) {  // 64-u16 rows
  return o ^ ((((o) >> 6) & 7) << 3);
}
__device__ __forceinline__ int swzK(int o) {  // 128-u16 rows
  return o ^ ((((o) >> 7) & 7) << 3);
}

// ---------------------------------------------------------------- dtype sniff
// flags[i]=1 -> input i is fp32 (detected from raw u16 stream signatures).
__global__ void sniff5(const u16* x, const u16* wq, const u16* wo,
                       const u16* qg, const u16* kg, int* flags) {
  const u16* p;
  int S;
  switch (blockIdx.x) {
    case 0: p = x;  S = 2048; break;
    case 1: p = wq; S = 2048; break;
    case 2: p = wo; S = 2048; break;
    case 3: p = qg; S = 128;  break;
    default: p = kg; S = 128; break;
  }
  __shared__ int cbig, czero;
  if (threadIdx.x == 0) { cbig = 0; czero = 0; }
  __syncthreads();
  int cb = 0, cz = 0;
  for (int i = threadIdx.x; i < S; i += 256) {
    const u16 u = p[i];
    if (((u >> 7) & 0xFF) >= 0xC0) ++cb;
    if (!(i & 1) && u == 0) ++cz;
  }
  atomicAdd(&cbig, cb);
  atomicAdd(&czero, cz);
  __syncthreads();
  if (threadIdx.x == 0)
    flags[blockIdx.x] = (cbig > S / 32 || czero > 3 * S / 8) ? 1 : 0;
}

// ---------------------------------------------------------------- convert
__global__ __launch_bounds__(256) void conv_in(const void* __restrict__ src,
                                               u16* __restrict__ dst,
                                               const int* __restrict__ flags,
                                               int fidx, int n) {
  const int fp32 = flags[fidx];
  int i = blockIdx.x * 256 + threadIdx.x;
  const int stride = gridDim.x * 256;
  if (fp32) {
    const float* s = (const float*)src;
    for (; i < n; i += stride) dst[i] = f2b(s[i]);
  } else {
    const u16* s = (const u16*)src;
    for (; i < n; i += stride) dst[i] = s[i];
  }
}

// ---------------------------------------------------------------- transpose_in
// dst[c][r] = bf16(src[r*ss + c]); dual-dtype. 64x64 tiles.
__global__ __launch_bounds__(256) void transpose_in(
    const void* __restrict__ src, u16* __restrict__ dst,
    const int* __restrict__ flags, int fidx, int ss, int ds) {
  __shared__ u16 tile[64][65];
  const int fp32 = flags[fidx];
  const int rb = blockIdx.y * 64, cb = blockIdx.x * 64;
  const int cl = threadIdx.x & 63, r0 = threadIdx.x >> 6;
  if (fp32) {
    const float* s = (const float*)src;
#pragma unroll
    for (int i = 0; i < 16; ++i) {
      int r = r0 + i * 4;
      tile[r][cl] = f2b(s[(long long)(rb + r) * ss + cb + cl]);
    }
  } else {
    const u16* s = (const u16*)src;
#pragma unroll
    for (int i = 0; i < 16; ++i) {
      int r = r0 + i * 4;
      tile[r][cl] = s[(long long)(rb + r) * ss + cb + cl];
    }
  }
  __syncthreads();
#pragma unroll
  for (int i = 0; i < 16; ++i) {
    int r2 = r0 + i * 4;
    dst[(long long)(cb + r2) * ds + rb + cl] = tile[cl][r2];
  }
}

// ---------------------------------------------------------------- fused QKV GEMM + norm/rope/transpose epilogue
// r12: epilogue rebuilt so its PEAK LIVENESS <= K-loop's (~100 VGPR); no
// launch_bounds force (r11's (256,4) made the compiler allocate 64 VGPR and
// spill acc -> WRITE_SIZE 176MB; r10's unforced 148 VGPR halved occupancy).
// Q/K path: row-SS + fp32 normalize (acc live) -> dump normalized values to
// smem as bf16 (128x128 u16 = 32KB, chunk-swizzled c^=row&7) -- acc DIES
// there -> low-pressure RoPE phase (8 invf + 2 bf16x8 live) reads (d,d^64)
// pairs from LDS, __sincosf, coalesced bf16x8 stores. bf16 rounding before
// RoPE == the r5-r9 split flow (q_buf was bf16), numerics unchanged.
// Gamma read folded in (dual-dtype via flags) -> 2 fewer dispatches.
__global__ __launch_bounds__(256) void gemm_qkv(
    const u16* __restrict__ A, const u16* __restrict__ Bt,
    const u16* __restrict__ gq, const u16* __restrict__ gk,
    const int* __restrict__ flags, u16* __restrict__ Cq, u16* __restrict__ Ck,
    u16* __restrict__ Cv, int K) {
  __shared__ __align__(16) u16 smem[2 * 128 * 64];  // As|Bs; reused by epilogue
  u16* As = smem;
  u16* Bs = smem + 128 * 64;
  const int bid = blockIdx.x;
  const int xcd = bid & 7, lid = bid >> 3;      // lid in [0,192)
  const int mb = lid / 6, nsub = lid - mb * 6;  // mb [0,32), nsub [0,6)
  const int nb = xcd * 6 + nsub;                // [0,48)
  const int m0 = mb * 128;
  const int n0g = nb * 128;                     // Bt row base (0..6143)
  const int sel = nb >> 4;                      // 0=q 1=k 2=v
  const int h = nb & 15;                        // head
  const int tid = threadIdx.x;
  const int w = tid >> 6, l = tid & 63;
  const int lane15 = l & 15, quad = l >> 4;
  const int wm = (w >> 1) * 64, wn = (w & 1) * 64;
  const int r8 = l >> 3, c8 = l & 7;
  const int sk = (c8 ^ r8) * 8;  // pre-swizzled global chunk
  const u16* gA = A + (size_t)(m0 + r8) * K + sk;
  const u16* gB = Bt + (size_t)(n0g + r8) * K + sk;
  f32x4 acc[4][4] = {};
  const int nK = K >> 6;
  for (int kb = 0; kb < nK; ++kb) {
    __syncthreads();  // WAR: previous iter's readers done
#pragma unroll
    for (int i = 0; i < 4; ++i) {
      const int g = i * 4 + w;
      gld_lds16(gA + (size_t)g * 8 * K, &As[g * 512]);
      gld_lds16(gB + (size_t)g * 8 * K, &Bs[g * 512]);
    }
    __syncthreads();  // drains vmcnt -> tile ready
#pragma unroll
    for (int kk = 0; kk < 2; ++kk) {
      bf16x8 af[4], bfr[4];
#pragma unroll
      for (int mi = 0; mi < 4; ++mi)
        af[mi] = *(const bf16x8*)&As[swzV((wm + mi * 16 + lane15) * 64 +
                                          kk * 32 + quad * 8)];
#pragma unroll
      for (int ni = 0; ni < 4; ++ni)
        bfr[ni] = *(const bf16x8*)&Bs[swzV((wn + ni * 16 + lane15) * 64 +
                                           kk * 32 + quad * 8)];
#pragma unroll
      for (int mi = 0; mi < 4; ++mi)
#pragma unroll
        for (int ni = 0; ni < 4; ++ni)
          acc[mi][ni] = __builtin_amdgcn_mfma_f32_16x16x32_bf16(
              af[mi], bfr[ni], acc[mi][ni], 0, 0, 0);
    }
    gA += 64;
    gB += 64;
  }

  // ---------------- fused epilogue ----------------
  __syncthreads();  // all K-loop LDS reads done; smem reusable
  if (sel == 2) {
    // V: transpose to v_t[h][d][n] via swizzled LDS
    u16* t = smem;
#pragma unroll
    for (int mi = 0; mi < 4; ++mi)
#pragma unroll
      for (int ni = 0; ni < 4; ++ni)
#pragma unroll
        for (int r = 0; r < 4; ++r) {
          const int row = wm + mi * 16 + quad * 4 + r;
          const int col = wn + ni * 16 + lane15;
          t[col * 128 + (row ^ ((col & 7) << 4))] = f2b(acc[mi][ni][r]);
        }
    __syncthreads();
    const int d = tid & 127, half = tid >> 7;
    u16* vdst = Cv + ((size_t)h * 128 + d) * 4096 + m0 + half * 64;
#pragma unroll
    for (int c8i = 0; c8i < 8; ++c8i) {
      const int n0c = half * 64 + c8i * 8;
      *(bf16x8*)(vdst + c8i * 8) =
          *(const bf16x8*)&t[d * 128 + (n0c ^ ((d & 7) << 4))];
    }
  } else {
    // Q/K: RMSNorm + RoPE + repack to (h,n,d)
    const void* graw = sel == 0 ? (const void*)gq : (const void*)gk;
    const int gfp32 = flags[sel == 0 ? 3 : 4];
    u16* dst = sel == 0 ? Cq : Ck;
    float* fss = (float*)smem;  // [128][2]
    // per-row sum of squares (this wave's 64-col half)
#pragma unroll
    for (int mi = 0; mi < 4; ++mi)
#pragma unroll
      for (int r = 0; r < 4; ++r) {
        float ss = 0.f;
#pragma unroll
        for (int ni = 0; ni < 4; ++ni) ss += acc[mi][ni][r] * acc[mi][ni][r];
#pragma unroll
        for (int mk = 1; mk < 16; mk <<= 1) ss += __shfl_xor(ss, mk);
        if (lane15 == 0)
          fss[(wm + mi * 16 + quad * 4 + r) * 2 + (w & 1)] = ss;
      }
    __syncthreads();
    // normalize + gamma (fp32, in place); dual-dtype gamma via flags
    float gv[4];
#pragma unroll
    for (int ni = 0; ni < 4; ++ni) {
      const int col = wn + ni * 16 + lane15;
      gv[ni] = gfp32 ? ((const float*)graw)[col] : b2f(((const u16*)graw)[col]);
    }
#pragma unroll
    for (int mi = 0; mi < 4; ++mi)
#pragma unroll
      for (int r = 0; r < 4; ++r) {
        const int row = wm + mi * 16 + quad * 4 + r;
        const float rstd =
            rsqrtf((fss[row * 2] + fss[row * 2 + 1]) * (1.f / 128.f) + 1e-6f);
#pragma unroll
        for (int ni = 0; ni < 4; ++ni) acc[mi][ni][r] *= rstd * gv[ni];
      }
    __syncthreads();  // fss reads done before nt overwrites smem
    // dump normalized bf16 to smem, chunk-swizzled (c ^= row&7); acc dies
    u16* nt = smem;  // [128][128] u16 = 32KB
#pragma unroll
    for (int mi = 0; mi < 4; ++mi)
#pragma unroll
      for (int ni = 0; ni < 4; ++ni)
#pragma unroll
        for (int r = 0; r < 4; ++r) {
          const int row = wm + mi * 16 + quad * 4 + r;
          const int col = wn + ni * 16 + lane15;
          nt[row * 128 + (((col >> 3) ^ (row & 7)) << 3) + (col & 7)] =
              f2b(acc[mi][ni][r]);
        }
    __syncthreads();
    // RoPE + store (low pressure: acc dead). Thread -> 8 consecutive d.
    const int d0 = (tid & 15) * 8;  // chunk base; entirely in one 64-half
    float invf[8];
#pragma unroll
    for (int j = 0; j < 8; ++j)
      invf[j] = __expf(-(float)((d0 + j) & 63) * 0.14391156831212787f);
    const int rbase = tid >> 4;  // 0..15
#pragma unroll
    for (int pass = 0; pass < 8; ++pass) {
      const int row = rbase + pass * 16;
      const int p = m0 + row;
      bf16x8 va = *(const bf16x8*)&nt[row * 128 +
                                      (((d0 >> 3) ^ (row & 7)) << 3)];
      bf16x8 vb = *(const bf16x8*)&nt[row * 128 +
                                      ((((d0 ^ 64) >> 3) ^ (row & 7)) << 3)];
      bf16x8 vo;
#pragma unroll
      for (int j = 0; j < 8; ++j) {
        float s, c;
        __sincosf((float)p * invf[j], &s, &c);
        const float a = b2f((u16)va[j]);
        const float bb = b2f((u16)vb[j]);
        vo[j] = (short)f2b(d0 < 64 ? a * c - bb * s : a * c + bb * s);
      }
      *(bf16x8*)&dst[((size_t)h * 4096 + p) * 128 + d0] = vo;
    }
  }
}

// ---------------------------------------------------------------- GEMM (fp32 out)
// Final projection: C(4096x2048 fp32) = A * Bt^T. BK=64. 512 blocks with
// XCD slab mapping (xcd owns 2 n-blocks, 1 MB B L2-set).
__global__ __launch_bounds__(256) void gemm_bt_f32(
    const u16* __restrict__ A, const u16* __restrict__ Bt,
    float* __restrict__ C, int K) {
  __shared__ __align__(16) u16 As[128 * 64];
  __shared__ __align__(16) u16 Bs[128 * 64];
  const int bid = blockIdx.x;
  const int xcd = bid & 7, lid = bid >> 3;      // lid in [0,64)
  const int mb = lid >> 1, nsub = lid & 1;
  const int nb = xcd * 2 + nsub;                // [0,16)
  const int m0 = mb * 128, n0 = nb * 128;
  const int tid = threadIdx.x;
  const int w = tid >> 6, l = tid & 63;
  const int lane15 = l & 15, quad = l >> 4;
  const int wm = (w >> 1) * 64, wn = (w & 1) * 64;
  const int r8 = l >> 3, c8 = l & 7;
  const int sk = (c8 ^ r8) * 8;
  const u16* gA = A + (size_t)(m0 + r8) * K + sk;
  const u16* gB = Bt + (size_t)(n0 + r8) * K + sk;
  f32x4 acc[4][4] = {};
  const int nK = K >> 6;
  for (int kb = 0; kb < nK; ++kb) {
    __syncthreads();
#pragma unroll
    for (int i = 0; i < 4; ++i) {
      const int g = i * 4 + w;
      gld_lds16(gA + (size_t)g * 8 * K, &As[g * 512]);
      gld_lds16(gB + (size_t)g * 8 * K, &Bs[g * 512]);
    }
    __syncthreads();
#pragma unroll
    for (int kk = 0; kk < 2; ++kk) {
      bf16x8 af[4], bfr[4];
#pragma unroll
      for (int mi = 0; mi < 4; ++mi)
        af[mi] = *(const bf16x8*)&As[swzV((wm + mi * 16 + lane15) * 64 +
                                          kk * 32 + quad * 8)];
#pragma unroll
      for (int ni = 0; ni < 4; ++ni)
        bfr[ni] = *(const bf16x8*)&Bs[swzV((wn + ni * 16 + lane15) * 64 +
                                           kk * 32 + quad * 8)];
#pragma unroll
      for (int mi = 0; mi < 4; ++mi)
#pragma unroll
        for (int ni = 0; ni < 4; ++ni)
          acc[mi][ni] = __builtin_amdgcn_mfma_f32_16x16x32_bf16(
              af[mi], bfr[ni], acc[mi][ni], 0, 0, 0);
    }
    gA += 64;
    gB += 64;
  }
#pragma unroll
  for (int mi = 0; mi < 4; ++mi)
#pragma unroll
    for (int ni = 0; ni < 4; ++ni)
#pragma unroll
      for (int r = 0; r < 4; ++r)
        C[(size_t)(m0 + wm + mi * 16 + quad * 4 + r) * 2048 +
          (n0 + wn + ni * 16 + lane15)] = acc[mi][ni][r];
}

// ---------------------------------------------------------------- flash attn
// EXACT r5 kernel (measured 205 us, FETCH 24.7MB): causal, BM=128, BN=64,
// 4 waves x 32 rows, 256 threads, launch_bounds(256,2). Sits at the
// L2-locality equilibrium (~32 phase-aligned blocks/XCD share one K/V
// stream). r6 (grid x2), r7 (dbuf pipeline), r8 (8 waves) all lost to it.
// FROZEN: do not raise occupancy without re-deriving XCD residency.
__global__ __launch_bounds__(256, 2) void flash_attn(
    const u16* __restrict__ q_r, const u16* __restrict__ k_r,
    const u16* __restrict__ v_t, u16* __restrict__ attn) {
  __shared__ __align__(16) u16 Kt[64 * 128];  // [key][hd] (swizzled)
  __shared__ __align__(16) u16 Vt[128 * 64];  // [hd][key] (swizzled)
  __shared__ __align__(16) u16 Pt[128 * 64];  // [q][key]  (swizzled)
  const int b = blockIdx.x;
  const int h = b & 15;
  const int qt = (b < 256) ? (31 - (b >> 4)) : ((b - 256) >> 4);
  const int m0 = qt * 128;
  const int tid = threadIdx.x, w = tid >> 6, l = tid & 63;
  const int lane15 = l & 15, quad = l >> 4;

  bf16x8 aq[2][4];
#pragma unroll
  for (int mi = 0; mi < 2; ++mi)
#pragma unroll
    for (int ks = 0; ks < 4; ++ks)
      aq[mi][ks] = *(const bf16x8*)&q_r[((size_t)h * 4096 + m0 + w * 32 +
                                         mi * 16 + lane15) * 128 +
                                        ks * 32 + quad * 8];

  f32x4 acc_o[2][8] = {};
  float m_i[2][4], l_i[2][4];
#pragma unroll
  for (int mi = 0; mi < 2; ++mi)
#pragma unroll
    for (int r = 0; r < 4; ++r) {
      m_i[mi][r] = NEGINF;
      l_i[mi][r] = 0.f;
    }

  const int jend = m0 + 64;
  for (int j0 = 0; j0 <= jend; j0 += 64) {
    __syncthreads();  // A: all waves done reading prev tile's LDS
#pragma unroll
    for (int i = 0; i < 4; ++i) {
      const int rg = i * 4 + w;             // 16 row-groups of 512 u16
      const int keyr = rg * 4 + (l >> 4);   // K tile row (0..63)
      const int kc = (l & 15) ^ (keyr & 7); // pre-swizzled 16B chunk
      const int dr = rg * 8 + (l >> 3);     // V tile row d (0..127)
      const int vc = (l & 7) ^ (dr & 7);
      gld_lds16(&k_r[((size_t)h * 4096 + j0 + keyr) * 128 + kc * 8],
                &Kt[rg * 512]);
      gld_lds16(&v_t[((size_t)h * 128 + dr) * 4096 + j0 + vc * 8],
                &Vt[rg * 512]);
    }
    __syncthreads();  // B: drains vmcnt -> LDS tile ready

    // S = Q K^T
    f32x4 s2[2][4] = {};
#pragma unroll
    for (int ni = 0; ni < 4; ++ni) {
#pragma unroll
      for (int ks = 0; ks < 4; ++ks) {
        bf16x8 bk = *(const bf16x8*)&Kt[swzK((ni * 16 + lane15) * 128 +
                                             ks * 32 + quad * 8)];
        s2[0][ni] = __builtin_amdgcn_mfma_f32_16x16x32_bf16(aq[0][ks], bk,
                                                            s2[0][ni], 0, 0, 0);
        s2[1][ni] = __builtin_amdgcn_mfma_f32_16x16x32_bf16(aq[1][ks], bk,
                                                            s2[1][ni], 0, 0, 0);
      }
    }

    const float sc = 0.08838834764831845f;  // 1/sqrt(128)
    const bool mt = (j0 >= m0);
#pragma unroll
    for (int mi = 0; mi < 2; ++mi) {
#pragma unroll
      for (int r = 0; r < 4; ++r) {
        const int lrow = w * 32 + mi * 16 + quad * 4 + r;
        float xv[4], mx4 = NEGINF;
#pragma unroll
        for (int ni = 0; ni < 4; ++ni) {
          float xx = s2[mi][ni][r] * sc;
          if (mt && (j0 + ni * 16 + lane15 > m0 + lrow)) xx = NEGINF;
          xv[ni] = xx;
          mx4 = fmaxf(mx4, xx);
        }
        const float mold = m_i[mi][r];
        // defer-max (T13, THR=8): rescale only if a lane in this 16-lane
        // row group exceeds mold+8 (exp then bounded by e^8).
        const unsigned long long bal = __ballot(mx4 > mold + 8.0f);
        float mcur = mold;
        if (((unsigned)(bal >> (quad * 16)) & 0xFFFFu) != 0u) {
          float mx = mx4;
#pragma unroll
          for (int mk = 1; mk < 16; mk <<= 1)
            mx = fmaxf(mx, __shfl_xor(mx, mk));
          const float mnew = fmaxf(mold, mx);
          const float alpha = __expf(mold - mnew);
          l_i[mi][r] *= alpha;
          m_i[mi][r] = mnew;
          mcur = mnew;
#pragma unroll
          for (int ni = 0; ni < 8; ++ni) acc_o[mi][ni][r] *= alpha;
        }
        float rs = 0.f;
#pragma unroll
        for (int ni = 0; ni < 4; ++ni) {
          const float p = __expf(xv[ni] - mcur);
          Pt[swzV(lrow * 64 + ni * 16 + lane15)] = f2b(p);
          rs += p;
        }
        l_i[mi][r] += rs;  // per-lane partial; group-reduced in epilogue
      }
    }
    // no barrier: Pt rows are same-wave (written & read by wave w only)

    // O += P V
#pragma unroll
    for (int ks = 0; ks < 2; ++ks) {
      bf16x8 ap0 = *(const bf16x8*)&Pt[swzV((w * 32 + lane15) * 64 + ks * 32 +
                                            quad * 8)];
      bf16x8 ap1 = *(const bf16x8*)&Pt[swzV((w * 32 + 16 + lane15) * 64 +
                                            ks * 32 + quad * 8)];
#pragma unroll
      for (int ni = 0; ni < 8; ++ni) {
        bf16x8 bv = *(const bf16x8*)&Vt[swzV((ni * 16 + lane15) * 64 +
                                             ks * 32 + quad * 8)];
        acc_o[0][ni] = __builtin_amdgcn_mfma_f32_16x16x32_bf16(
            ap0, bv, acc_o[0][ni], 0, 0, 0);
        acc_o[1][ni] = __builtin_amdgcn_mfma_f32_16x16x32_bf16(
            ap1, bv, acc_o[1][ni], 0, 0, 0);
      }
    }
  }

  // epilogue: finish the deferred l_i group-reduction, then normalize+store
#pragma unroll
  for (int mi = 0; mi < 2; ++mi)
#pragma unroll
    for (int r = 0; r < 4; ++r) {
      float s = l_i[mi][r];
#pragma unroll
      for (int mk = 1; mk < 16; mk <<= 1) s += __shfl_xor(s, mk);
      l_i[mi][r] = s;
    }
#pragma unroll
  for (int mi = 0; mi < 2; ++mi)
#pragma unroll
    for (int ni = 0; ni < 8; ++ni)
#pragma unroll
      for (int r = 0; r < 4; ++r)
        attn[(size_t)(m0 + w * 32 + mi * 16 + quad * 4 + r) * 2048 + h * 128 +
             ni * 16 + lane15] = f2b(acc_o[mi][ni][r] / l_i[mi][r]);
}

// ---------------------------------------------------------------- launch
// Buffer plan (r10+, fused epilogue):
//   ws A0 [0,16.8M):       xb (gemm_qkv A input; dead after)
//   ws A1 [16.8,33.6M):    q_r   (gemm_qkv epilogue out; read by flash)
//   ws A2 [33.6,58.72M):   wT (B input) -> attn [33.6,50.3) + woT [50.3,58.72)
//                          (both written only AFTER gemm_qkv, wT dead)
//   flags at 58.72M
//   d_out D0 [0,16.8M):    k_r   (dead before final gemm writes)
//   d_out D1 [16.8,33.5M): v_t   (dead before final gemm writes)
// gemm_qkv reads A0+A2+raw gammas, writes A1/D0/D1 -> no alias race.
// flash reads A1/D0/D1, writes attn (A2a, dead wT) -> no race.
// Final gemm reads only ws (attn+woT), writes fp32 d_out over dead k_r/v_t.
extern "C" void kernel_launch(void* const* d_in, const int* in_sizes, int n_in,
                              void* d_out, int out_size, void* d_ws,
                              size_t ws_size, hipStream_t stream) {
  (void)out_size; (void)ws_size;
  int ix = 0, iwq = 1, iwo = 2, ig1 = 3, ig2 = 4;
  {
    int g1 = -1, g2 = -1, xx = -1, wqq = -1, woo = -1;
    for (int i = 0; i < n_in; ++i) {
      const int s = in_sizes[i];
      if (s == 8388608) xx = i;
      else if (s == 12582912) wqq = i;
      else if (s == 4194304) woo = i;
      else if (s == 128) { if (g1 < 0) g1 = i; else g2 = i; }
    }
    if (xx >= 0 && wqq >= 0 && woo >= 0 && g1 >= 0 && g2 >= 0) {
      ix = xx; iwq = wqq; iwo = woo; ig1 = g1; ig2 = g2;
    }
  }
  const void* x = d_in[ix];
  const void* wq = d_in[iwq];
  const void* wo = d_in[iwo];
  const void* qg = d_in[ig1];
  const void* kg = d_in[ig2];
  float* out = (float*)d_out;
  char* ws = (char*)d_ws;
  u16* xb = (u16*)(ws);                 // A0
  u16* q_r = (u16*)(ws + 16777216LL);   // A1
  u16* wT = (u16*)(ws + 33554432LL);    // A2 (6144x2048)
  u16* attn = (u16*)(ws + 33554432LL);  // A2a, over dead wT
  u16* woT = (u16*)(ws + 50331648LL);   // A2b, over dead wT tail
  int* flags = (int*)(ws + 58720256LL);
  u16* k_r = (u16*)d_out;               // D0
  u16* v_t = (u16*)d_out + 8388608;     // D1

  sniff5<<<5, 256, 0, stream>>>((const u16*)x, (const u16*)wq, (const u16*)wo,
                                (const u16*)qg, (const u16*)kg, flags);
  conv_in<<<8192, 256, 0, stream>>>(x, xb, flags, 0, 4096 * 2048);
  // wq^T: (2048x6144) -> wT (6144x2048)
  transpose_in<<<dim3(96, 32), 256, 0, stream>>>(wq, wT, flags, 1, 6144, 2048);
  // fused q/k/v projection + rmsnorm/rope/transpose epilogue (gammas raw)
  gemm_qkv<<<dim3(1536), 256, 0, stream>>>(xb, wT, (const u16*)qg,
                                           (const u16*)kg, flags, q_r, k_r,
                                           v_t, 2048);
  // w_out^T (after gemm_qkv: overlays dead wT tail)
  transpose_in<<<dim3(32, 32), 256, 0, stream>>>(wo, woT, flags, 2, 2048, 2048);
  // causal flash attention -> attn (n, 2048), over dead wT head
  flash_attn<<<dim3(512), 256, 0, stream>>>(q_r, k_r, v_t, attn);
  // out = attn @ w_out -> fp32 d_out (reads only ws)
  gemm_bt_f32<<<dim3(512), 256, 0, stream>>>(attn, woT, out, 2048);
}

// Round 13
// 521.650 us; speedup vs baseline: 1.2362x; 1.2362x over previous
//
#include <hip/hip_runtime.h>
#include <stdint.h>

typedef short bf16x8 __attribute__((ext_vector_type(8)));
typedef float f32x4 __attribute__((ext_vector_type(4)));
typedef unsigned short u16;

__device__ __forceinline__ float b2f(u16 u) {
  return __uint_as_float(((unsigned)u) << 16);
}
__device__ __forceinline__ u16 f2b(float f) {
  unsigned u = __float_as_uint(f);
  return (u16)((u + 0x7fffu + ((u >> 16) & 1u)) >> 16);  // RNE
}

#define NEGINF (-1.0e30f)

__device__ __forceinline__ void gld_lds16(const u16* g, u16* l) {
  __builtin_amdgcn_global_load_lds(
      (const __attribute__((address_space(1))) unsigned int*)(const void*)g,
      (__attribute__((address_space(3))) unsigned int*)(void*)l, 16, 0, 0);
}

// swizzles: XOR 16B-chunk bits with row&7. Involutions.
__device__ __forceinline__ int swzV(int o) {  // 64-u16 rows
  return o ^ ((((o) >> 6) & 7) << 3);
}
__device__ __forceinline__ int swzK(int o) {  // 128-u16 rows
  return o ^ ((((o) >> 7) & 7) << 3);
}

// ---------------------------------------------------------------- dtype sniff
// flags[i]=1 -> input i is fp32 (detected from raw u16 stream signatures).
__global__ void sniff5(const u16* x, const u16* wq, const u16* wo,
                       const u16* qg, const u16* kg, int* flags) {
  const u16* p;
  int S;
  switch (blockIdx.x) {
    case 0: p = x;  S = 2048; break;
    case 1: p = wq; S = 2048; break;
    case 2: p = wo; S = 2048; break;
    case 3: p = qg; S = 128;  break;
    default: p = kg; S = 128; break;
  }
  __shared__ int cbig, czero;
  if (threadIdx.x == 0) { cbig = 0; czero = 0; }
  __syncthreads();
  int cb = 0, cz = 0;
  for (int i = threadIdx.x; i < S; i += 256) {
    const u16 u = p[i];
    if (((u >> 7) & 0xFF) >= 0xC0) ++cb;
    if (!(i & 1) && u == 0) ++cz;
  }
  atomicAdd(&cbig, cb);
  atomicAdd(&czero, cz);
  __syncthreads();
  if (threadIdx.x == 0)
    flags[blockIdx.x] = (cbig > S / 32 || czero > 3 * S / 8) ? 1 : 0;
}

// ---------------------------------------------------------------- convert
__global__ __launch_bounds__(256) void conv_in(const void* __restrict__ src,
                                               u16* __restrict__ dst,
                                               const int* __restrict__ flags,
                                               int fidx, int n) {
  const int fp32 = flags[fidx];
  int i = blockIdx.x * 256 + threadIdx.x;
  const int stride = gridDim.x * 256;
  if (fp32) {
    const float* s = (const float*)src;
    for (; i < n; i += stride) dst[i] = f2b(s[i]);
  } else {
    const u16* s = (const u16*)src;
    for (; i < n; i += stride) dst[i] = s[i];
  }
}

// ---------------------------------------------------------------- transpose_in
// dst[c][r] = bf16(src[r*ss + c]); dual-dtype. 64x64 tiles.
__global__ __launch_bounds__(256) void transpose_in(
    const void* __restrict__ src, u16* __restrict__ dst,
    const int* __restrict__ flags, int fidx, int ss, int ds) {
  __shared__ u16 tile[64][65];
  const int fp32 = flags[fidx];
  const int rb = blockIdx.y * 64, cb = blockIdx.x * 64;
  const int cl = threadIdx.x & 63, r0 = threadIdx.x >> 6;
  if (fp32) {
    const float* s = (const float*)src;
#pragma unroll
    for (int i = 0; i < 16; ++i) {
      int r = r0 + i * 4;
      tile[r][cl] = f2b(s[(long long)(rb + r) * ss + cb + cl]);
    }
  } else {
    const u16* s = (const u16*)src;
#pragma unroll
    for (int i = 0; i < 16; ++i) {
      int r = r0 + i * 4;
      tile[r][cl] = s[(long long)(rb + r) * ss + cb + cl];
    }
  }
  __syncthreads();
#pragma unroll
  for (int i = 0; i < 16; ++i) {
    int r2 = r0 + i * 4;
    dst[(long long)(cb + r2) * ds + rb + cl] = tile[cl][r2];
  }
}

// ---------------------------------------------------------------- fused QKV GEMM + norm/rope/transpose epilogue
// r13: final fusion attempt, mechanism-targeted at r12's VGPR=136. r12's
// peak was the fp32-normalize phase: acc(64) live + 16-wide ILP-expanded
// fss-load/rsqrt chains. r13 dumps acc -> LDS bf16 IMMEDIATELY after the
// K-loop (acc dies at K-loop pressure ~80 regs), then does SS + normalize +
// RoPE in one low-pressure LDS-read phase (~50 regs: 24 hoisted
// gamma/invf + va/vb/vo). Numerics: SS over bf16-rounded values == the r9
// split flow (rms_rope read bf16 q_buf; passed absmax 0.015625).
// Pre-commit: VGPR>128 or dur>200us -> permanent revert to r9 split.
__global__ __launch_bounds__(256) void gemm_qkv(
    const u16* __restrict__ A, const u16* __restrict__ Bt,
    const u16* __restrict__ gq, const u16* __restrict__ gk,
    const int* __restrict__ flags, u16* __restrict__ Cq, u16* __restrict__ Ck,
    u16* __restrict__ Cv, int K) {
  __shared__ __align__(16) u16 smem[2 * 128 * 64];  // As|Bs; reused by epilogue
  u16* As = smem;
  u16* Bs = smem + 128 * 64;
  const int bid = blockIdx.x;
  const int xcd = bid & 7, lid = bid >> 3;      // lid in [0,192)
  const int mb = lid / 6, nsub = lid - mb * 6;  // mb [0,32), nsub [0,6)
  const int nb = xcd * 6 + nsub;                // [0,48)
  const int m0 = mb * 128;
  const int n0g = nb * 128;                     // Bt row base (0..6143)
  const int sel = nb >> 4;                      // 0=q 1=k 2=v
  const int h = nb & 15;                        // head
  const int tid = threadIdx.x;
  const int w = tid >> 6, l = tid & 63;
  const int lane15 = l & 15, quad = l >> 4;
  const int wm = (w >> 1) * 64, wn = (w & 1) * 64;
  const int r8 = l >> 3, c8 = l & 7;
  const int sk = (c8 ^ r8) * 8;  // pre-swizzled global chunk
  const u16* gA = A + (size_t)(m0 + r8) * K + sk;
  const u16* gB = Bt + (size_t)(n0g + r8) * K + sk;
  f32x4 acc[4][4] = {};
  const int nK = K >> 6;
  for (int kb = 0; kb < nK; ++kb) {
    __syncthreads();  // WAR: previous iter's readers done
#pragma unroll
    for (int i = 0; i < 4; ++i) {
      const int g = i * 4 + w;
      gld_lds16(gA + (size_t)g * 8 * K, &As[g * 512]);
      gld_lds16(gB + (size_t)g * 8 * K, &Bs[g * 512]);
    }
    __syncthreads();  // drains vmcnt -> tile ready
#pragma unroll
    for (int kk = 0; kk < 2; ++kk) {
      bf16x8 af[4], bfr[4];
#pragma unroll
      for (int mi = 0; mi < 4; ++mi)
        af[mi] = *(const bf16x8*)&As[swzV((wm + mi * 16 + lane15) * 64 +
                                          kk * 32 + quad * 8)];
#pragma unroll
      for (int ni = 0; ni < 4; ++ni)
        bfr[ni] = *(const bf16x8*)&Bs[swzV((wn + ni * 16 + lane15) * 64 +
                                           kk * 32 + quad * 8)];
#pragma unroll
      for (int mi = 0; mi < 4; ++mi)
#pragma unroll
        for (int ni = 0; ni < 4; ++ni)
          acc[mi][ni] = __builtin_amdgcn_mfma_f32_16x16x32_bf16(
              af[mi], bfr[ni], acc[mi][ni], 0, 0, 0);
    }
    gA += 64;
    gB += 64;
  }

  // ---------------- fused epilogue ----------------
  __syncthreads();  // all K-loop LDS reads done; smem reusable
  if (sel == 2) {
    // V: transpose to v_t[h][d][n] via swizzled LDS
    u16* t = smem;
#pragma unroll
    for (int mi = 0; mi < 4; ++mi)
#pragma unroll
      for (int ni = 0; ni < 4; ++ni)
#pragma unroll
        for (int r = 0; r < 4; ++r) {
          const int row = wm + mi * 16 + quad * 4 + r;
          const int col = wn + ni * 16 + lane15;
          t[col * 128 + (row ^ ((col & 7) << 4))] = f2b(acc[mi][ni][r]);
        }
    __syncthreads();
    const int d = tid & 127, half = tid >> 7;
    u16* vdst = Cv + ((size_t)h * 128 + d) * 4096 + m0 + half * 64;
#pragma unroll
    for (int c8i = 0; c8i < 8; ++c8i) {
      const int n0c = half * 64 + c8i * 8;
      *(bf16x8*)(vdst + c8i * 8) =
          *(const bf16x8*)&t[d * 128 + (n0c ^ ((d & 7) << 4))];
    }
  } else {
    // Q/K: dump bf16 to LDS FIRST (acc dies at K-loop pressure), then
    // low-pressure SS + norm + RoPE entirely from LDS.
    const void* graw = sel == 0 ? (const void*)gq : (const void*)gk;
    const int gfp32 = flags[sel == 0 ? 3 : 4];
    u16* dst = sel == 0 ? Cq : Ck;
    u16* nt = smem;  // [128][128] u16 = 32KB, chunk-swizzled c^=row&7
#pragma unroll
    for (int mi = 0; mi < 4; ++mi)
#pragma unroll
      for (int ni = 0; ni < 4; ++ni)
#pragma unroll
        for (int r = 0; r < 4; ++r) {
          const int row = wm + mi * 16 + quad * 4 + r;
          const int col = wn + ni * 16 + lane15;
          nt[row * 128 + (((col >> 3) ^ (row & 7)) << 3) + (col & 7)] =
              f2b(acc[mi][ni][r]);
        }
    __syncthreads();
    // low-pressure phase: lane owns 8 consecutive d (one 64-half);
    // 16 lanes (one shfl group) cover one row's 128 d.
    const int d0 = (tid & 15) * 8;
    const int rbase = tid >> 4;  // 0..15
    float gown[8], gpar[8], invf[8];
#pragma unroll
    for (int j = 0; j < 8; ++j) {
      const int c0 = d0 + j, c1 = c0 ^ 64;
      gown[j] = gfp32 ? ((const float*)graw)[c0] : b2f(((const u16*)graw)[c0]);
      gpar[j] = gfp32 ? ((const float*)graw)[c1] : b2f(((const u16*)graw)[c1]);
      invf[j] = __expf(-(float)(c0 & 63) * 0.14391156831212787f);
    }
#pragma unroll
    for (int pass = 0; pass < 8; ++pass) {
      const int row = rbase + pass * 16;
      const int p = m0 + row;
      bf16x8 va =
          *(const bf16x8*)&nt[row * 128 + (((d0 >> 3) ^ (row & 7)) << 3)];
      bf16x8 vb =
          *(const bf16x8*)&nt[row * 128 + ((((d0 ^ 64) >> 3) ^ (row & 7)) << 3)];
      float ss = 0.f;
#pragma unroll
      for (int j = 0; j < 8; ++j) {
        const float a = b2f((u16)va[j]);
        ss += a * a;
      }
#pragma unroll
      for (int mk = 1; mk < 16; mk <<= 1) ss += __shfl_xor(ss, mk);
      const float rstd = rsqrtf(ss * (1.f / 128.f) + 1e-6f);
      bf16x8 vo;
#pragma unroll
      for (int j = 0; j < 8; ++j) {
        float s, c;
        __sincosf((float)p * invf[j], &s, &c);
        const float a = b2f((u16)va[j]) * rstd * gown[j];
        const float bb = b2f((u16)vb[j]) * rstd * gpar[j];
        vo[j] = (short)f2b(d0 < 64 ? a * c - bb * s : a * c + bb * s);
      }
      *(bf16x8*)&dst[((size_t)h * 4096 + p) * 128 + d0] = vo;
    }
  }
}

// ---------------------------------------------------------------- GEMM (fp32 out)
// Final projection: C(4096x2048 fp32) = A * Bt^T. BK=64. 512 blocks with
// XCD slab mapping (xcd owns 2 n-blocks, 1 MB B L2-set).
__global__ __launch_bounds__(256) void gemm_bt_f32(
    const u16* __restrict__ A, const u16* __restrict__ Bt,
    float* __restrict__ C, int K) {
  __shared__ __align__(16) u16 As[128 * 64];
  __shared__ __align__(16) u16 Bs[128 * 64];
  const int bid = blockIdx.x;
  const int xcd = bid & 7, lid = bid >> 3;      // lid in [0,64)
  const int mb = lid >> 1, nsub = lid & 1;
  const int nb = xcd * 2 + nsub;                // [0,16)
  const int m0 = mb * 128, n0 = nb * 128;
  const int tid = threadIdx.x;
  const int w = tid >> 6, l = tid & 63;
  const int lane15 = l & 15, quad = l >> 4;
  const int wm = (w >> 1) * 64, wn = (w & 1) * 64;
  const int r8 = l >> 3, c8 = l & 7;
  const int sk = (c8 ^ r8) * 8;
  const u16* gA = A + (size_t)(m0 + r8) * K + sk;
  const u16* gB = Bt + (size_t)(n0 + r8) * K + sk;
  f32x4 acc[4][4] = {};
  const int nK = K >> 6;
  for (int kb = 0; kb < nK; ++kb) {
    __syncthreads();
#pragma unroll
    for (int i = 0; i < 4; ++i) {
      const int g = i * 4 + w;
      gld_lds16(gA + (size_t)g * 8 * K, &As[g * 512]);
      gld_lds16(gB + (size_t)g * 8 * K, &Bs[g * 512]);
    }
    __syncthreads();
#pragma unroll
    for (int kk = 0; kk < 2; ++kk) {
      bf16x8 af[4], bfr[4];
#pragma unroll
      for (int mi = 0; mi < 4; ++mi)
        af[mi] = *(const bf16x8*)&As[swzV((wm + mi * 16 + lane15) * 64 +
                                          kk * 32 + quad * 8)];
#pragma unroll
      for (int ni = 0; ni < 4; ++ni)
        bfr[ni] = *(const bf16x8*)&Bs[swzV((wn + ni * 16 + lane15) * 64 +
                                           kk * 32 + quad * 8)];
#pragma unroll
      for (int mi = 0; mi < 4; ++mi)
#pragma unroll
        for (int ni = 0; ni < 4; ++ni)
          acc[mi][ni] = __builtin_amdgcn_mfma_f32_16x16x32_bf16(
              af[mi], bfr[ni], acc[mi][ni], 0, 0, 0);
    }
    gA += 64;
    gB += 64;
  }
#pragma unroll
  for (int mi = 0; mi < 4; ++mi)
#pragma unroll
    for (int ni = 0; ni < 4; ++ni)
#pragma unroll
      for (int r = 0; r < 4; ++r)
        C[(size_t)(m0 + wm + mi * 16 + quad * 4 + r) * 2048 +
          (n0 + wn + ni * 16 + lane15)] = acc[mi][ni][r];
}

// ---------------------------------------------------------------- flash attn
// EXACT r5 kernel (measured 205 us, FETCH 24.7MB): causal, BM=128, BN=64,
// 4 waves x 32 rows, 256 threads, launch_bounds(256,2). Sits at the
// L2-locality equilibrium (~32 phase-aligned blocks/XCD share one K/V
// stream). r6 (grid x2), r7 (dbuf pipeline), r8 (8 waves) all lost to it.
// FROZEN: do not raise occupancy without re-deriving XCD residency.
__global__ __launch_bounds__(256, 2) void flash_attn(
    const u16* __restrict__ q_r, const u16* __restrict__ k_r,
    const u16* __restrict__ v_t, u16* __restrict__ attn) {
  __shared__ __align__(16) u16 Kt[64 * 128];  // [key][hd] (swizzled)
  __shared__ __align__(16) u16 Vt[128 * 64];  // [hd][key] (swizzled)
  __shared__ __align__(16) u16 Pt[128 * 64];  // [q][key]  (swizzled)
  const int b = blockIdx.x;
  const int h = b & 15;
  const int qt = (b < 256) ? (31 - (b >> 4)) : ((b - 256) >> 4);
  const int m0 = qt * 128;
  const int tid = threadIdx.x, w = tid >> 6, l = tid & 63;
  const int lane15 = l & 15, quad = l >> 4;

  bf16x8 aq[2][4];
#pragma unroll
  for (int mi = 0; mi < 2; ++mi)
#pragma unroll
    for (int ks = 0; ks < 4; ++ks)
      aq[mi][ks] = *(const bf16x8*)&q_r[((size_t)h * 4096 + m0 + w * 32 +
                                         mi * 16 + lane15) * 128 +
                                        ks * 32 + quad * 8];

  f32x4 acc_o[2][8] = {};
  float m_i[2][4], l_i[2][4];
#pragma unroll
  for (int mi = 0; mi < 2; ++mi)
#pragma unroll
    for (int r = 0; r < 4; ++r) {
      m_i[mi][r] = NEGINF;
      l_i[mi][r] = 0.f;
    }

  const int jend = m0 + 64;
  for (int j0 = 0; j0 <= jend; j0 += 64) {
    __syncthreads();  // A: all waves done reading prev tile's LDS
#pragma unroll
    for (int i = 0; i < 4; ++i) {
      const int rg = i * 4 + w;             // 16 row-groups of 512 u16
      const int keyr = rg * 4 + (l >> 4);   // K tile row (0..63)
      const int kc = (l & 15) ^ (keyr & 7); // pre-swizzled 16B chunk
      const int dr = rg * 8 + (l >> 3);     // V tile row d (0..127)
      const int vc = (l & 7) ^ (dr & 7);
      gld_lds16(&k_r[((size_t)h * 4096 + j0 + keyr) * 128 + kc * 8],
                &Kt[rg * 512]);
      gld_lds16(&v_t[((size_t)h * 128 + dr) * 4096 + j0 + vc * 8],
                &Vt[rg * 512]);
    }
    __syncthreads();  // B: drains vmcnt -> LDS tile ready

    // S = Q K^T
    f32x4 s2[2][4] = {};
#pragma unroll
    for (int ni = 0; ni < 4; ++ni) {
#pragma unroll
      for (int ks = 0; ks < 4; ++ks) {
        bf16x8 bk = *(const bf16x8*)&Kt[swzK((ni * 16 + lane15) * 128 +
                                             ks * 32 + quad * 8)];
        s2[0][ni] = __builtin_amdgcn_mfma_f32_16x16x32_bf16(aq[0][ks], bk,
                                                            s2[0][ni], 0, 0, 0);
        s2[1][ni] = __builtin_amdgcn_mfma_f32_16x16x32_bf16(aq[1][ks], bk,
                                                            s2[1][ni], 0, 0, 0);
      }
    }

    const float sc = 0.08838834764831845f;  // 1/sqrt(128)
    const bool mt = (j0 >= m0);
#pragma unroll
    for (int mi = 0; mi < 2; ++mi) {
#pragma unroll
      for (int r = 0; r < 4; ++r) {
        const int lrow = w * 32 + mi * 16 + quad * 4 + r;
        float xv[4], mx4 = NEGINF;
#pragma unroll
        for (int ni = 0; ni < 4; ++ni) {
          float xx = s2[mi][ni][r] * sc;
          if (mt && (j0 + ni * 16 + lane15 > m0 + lrow)) xx = NEGINF;
          xv[ni] = xx;
          mx4 = fmaxf(mx4, xx);
        }
        const float mold = m_i[mi][r];
        // defer-max (T13, THR=8): rescale only if a lane in this 16-lane
        // row group exceeds mold+8 (exp then bounded by e^8).
        const unsigned long long bal = __ballot(mx4 > mold + 8.0f);
        float mcur = mold;
        if (((unsigned)(bal >> (quad * 16)) & 0xFFFFu) != 0u) {
          float mx = mx4;
#pragma unroll
          for (int mk = 1; mk < 16; mk <<= 1)
            mx = fmaxf(mx, __shfl_xor(mx, mk));
          const float mnew = fmaxf(mold, mx);
          const float alpha = __expf(mold - mnew);
          l_i[mi][r] *= alpha;
          m_i[mi][r] = mnew;
          mcur = mnew;
#pragma unroll
          for (int ni = 0; ni < 8; ++ni) acc_o[mi][ni][r] *= alpha;
        }
        float rs = 0.f;
#pragma unroll
        for (int ni = 0; ni < 4; ++ni) {
          const float p = __expf(xv[ni] - mcur);
          Pt[swzV(lrow * 64 + ni * 16 + lane15)] = f2b(p);
          rs += p;
        }
        l_i[mi][r] += rs;  // per-lane partial; group-reduced in epilogue
      }
    }
    // no barrier: Pt rows are same-wave (written & read by wave w only)

    // O += P V
#pragma unroll
    for (int ks = 0; ks < 2; ++ks) {
      bf16x8 ap0 = *(const bf16x8*)&Pt[swzV((w * 32 + lane15) * 64 + ks * 32 +
                                            quad * 8)];
      bf16x8 ap1 = *(const bf16x8*)&Pt[swzV((w * 32 + 16 + lane15) * 64 +
                                            ks * 32 + quad * 8)];
#pragma unroll
      for (int ni = 0; ni < 8; ++ni) {
        bf16x8 bv = *(const bf16x8*)&Vt[swzV((ni * 16 + lane15) * 64 +
                                             ks * 32 + quad * 8)];
        acc_o[0][ni] = __builtin_amdgcn_mfma_f32_16x16x32_bf16(
            ap0, bv, acc_o[0][ni], 0, 0, 0);
        acc_o[1][ni] = __builtin_amdgcn_mfma_f32_16x16x32_bf16(
            ap1, bv, acc_o[1][ni], 0, 0, 0);
      }
    }
  }

  // epilogue: finish the deferred l_i group-reduction, then normalize+store
#pragma unroll
  for (int mi = 0; mi < 2; ++mi)
#pragma unroll
    for (int r = 0; r < 4; ++r) {
      float s = l_i[mi][r];
#pragma unroll
      for (int mk = 1; mk < 16; mk <<= 1) s += __shfl_xor(s, mk);
      l_i[mi][r] = s;
    }
#pragma unroll
  for (int mi = 0; mi < 2; ++mi)
#pragma unroll
    for (int ni = 0; ni < 8; ++ni)
#pragma unroll
      for (int r = 0; r < 4; ++r)
        attn[(size_t)(m0 + w * 32 + mi * 16 + quad * 4 + r) * 2048 + h * 128 +
             ni * 16 + lane15] = f2b(acc_o[mi][ni][r] / l_i[mi][r]);
}

// ---------------------------------------------------------------- launch
// Buffer plan (r10+, fused epilogue):
//   ws A0 [0,16.8M):       xb (gemm_qkv A input; dead after)
//   ws A1 [16.8,33.6M):    q_r   (gemm_qkv epilogue out; read by flash)
//   ws A2 [33.6,58.72M):   wT (B input) -> attn [33.6,50.3) + woT [50.3,58.72)
//                          (both written only AFTER gemm_qkv, wT dead)
//   flags at 58.72M
//   d_out D0 [0,16.8M):    k_r   (dead before final gemm writes)
//   d_out D1 [16.8,33.5M): v_t   (dead before final gemm writes)
// gemm_qkv reads A0+A2+raw gammas, writes A1/D0/D1 -> no alias race.
// flash reads A1/D0/D1, writes attn (A2a, dead wT) -> no race.
// Final gemm reads only ws (attn+woT), writes fp32 d_out over dead k_r/v_t.
extern "C" void kernel_launch(void* const* d_in, const int* in_sizes, int n_in,
                              void* d_out, int out_size, void* d_ws,
                              size_t ws_size, hipStream_t stream) {
  (void)out_size; (void)ws_size;
  int ix = 0, iwq = 1, iwo = 2, ig1 = 3, ig2 = 4;
  {
    int g1 = -1, g2 = -1, xx = -1, wqq = -1, woo = -1;
    for (int i = 0; i < n_in; ++i) {
      const int s = in_sizes[i];
      if (s == 8388608) xx = i;
      else if (s == 12582912) wqq = i;
      else if (s == 4194304) woo = i;
      else if (s == 128) { if (g1 < 0) g1 = i; else g2 = i; }
    }
    if (xx >= 0 && wqq >= 0 && woo >= 0 && g1 >= 0 && g2 >= 0) {
      ix = xx; iwq = wqq; iwo = woo; ig1 = g1; ig2 = g2;
    }
  }
  const void* x = d_in[ix];
  const void* wq = d_in[iwq];
  const void* wo = d_in[iwo];
  const void* qg = d_in[ig1];
  const void* kg = d_in[ig2];
  float* out = (float*)d_out;
  char* ws = (char*)d_ws;
  u16* xb = (u16*)(ws);                 // A0
  u16* q_r = (u16*)(ws + 16777216LL);   // A1
  u16* wT = (u16*)(ws + 33554432LL);    // A2 (6144x2048)
  u16* attn = (u16*)(ws + 33554432LL);  // A2a, over dead wT
  u16* woT = (u16*)(ws + 50331648LL);   // A2b, over dead wT tail
  int* flags = (int*)(ws + 58720256LL);
  u16* k_r = (u16*)d_out;               // D0
  u16* v_t = (u16*)d_out + 8388608;     // D1

  sniff5<<<5, 256, 0, stream>>>((const u16*)x, (const u16*)wq, (const u16*)wo,
                                (const u16*)qg, (const u16*)kg, flags);
  conv_in<<<8192, 256, 0, stream>>>(x, xb, flags, 0, 4096 * 2048);
  // wq^T: (2048x6144) -> wT (6144x2048)
  transpose_in<<<dim3(96, 32), 256, 0, stream>>>(wq, wT, flags, 1, 6144, 2048);
  // fused q/k/v projection + rmsnorm/rope/transpose epilogue (gammas raw)
  gemm_qkv<<<dim3(1536), 256, 0, stream>>>(xb, wT, (const u16*)qg,
                                           (const u16*)kg, flags, q_r, k_r,
                                           v_t, 2048);
  // w_out^T (after gemm_qkv: overlays dead wT tail)
  transpose_in<<<dim3(32, 32), 256, 0, stream>>>(wo, woT, flags, 2, 2048, 2048);
  // causal flash attention -> attn (n, 2048), over dead wT head
  flash_attn<<<dim3(512), 256, 0, stream>>>(q_r, k_r, v_t, attn);
  // out = attn @ w_out -> fp32 d_out (reads only ws)
  gemm_bt_f32<<<dim3(512), 256, 0, stream>>>(attn, woT, out, 2048);
}